// Round 6
// baseline (317.856 us; speedup 1.0000x reference)
//
#include <hip/hip_runtime.h>

#define NG 20000

// single-instruction rotate (v_alignbit_b32): rotl(x,r) == alignbit(x,x,32-r)
__device__ __forceinline__ unsigned rotl32(unsigned x, int r) {
  return __builtin_amdgcn_alignbit(x, x, 32 - r);
}

// ---------- JAX threefry2x32, key = (0, 42) ----------
__device__ __forceinline__ void threefry2x32(unsigned x0, unsigned x1,
                                             unsigned& o0, unsigned& o1) {
  const unsigned ks0 = 0u;
  const unsigned ks1 = 42u;
  const unsigned ks2 = 0x1BD11BDAu ^ 0u ^ 42u;
  x0 += ks0; x1 += ks1;
#define TFR(r) { x0 += x1; x1 = rotl32(x1, (r)); x1 ^= x0; }
  TFR(13) TFR(15) TFR(26) TFR(6)
  x0 += ks1; x1 += ks2 + 1u;
  TFR(17) TFR(29) TFR(16) TFR(24)
  x0 += ks2; x1 += ks0 + 2u;
  TFR(13) TFR(15) TFR(26) TFR(6)
  x0 += ks0; x1 += ks1 + 3u;
  TFR(17) TFR(29) TFR(16) TFR(24)
  x0 += ks1; x1 += ks2 + 4u;
  TFR(13) TFR(15) TFR(26) TFR(6)
  x0 += ks2; x1 += ks0 + 5u;
#undef TFR
  o0 = x0; o1 = x1;
}

// JAX threefry_partitionable: bits(i) = o0 ^ o1 of threefry((0,42),(0,i))
__device__ __forceinline__ unsigned tfbits(unsigned ctr) {
  unsigned o0, o1;
  threefry2x32(0u, ctr, o0, o1);
  return o0 ^ o1;
}

// fp32 fast-screen gumbel, constant-folded: g = -ln2*log2(-log2(u)) - ln(ln2)
__device__ __forceinline__ float gumbel32(unsigned bits) {
  float f = __uint_as_float((bits >> 9) | 0x3f800000u) - 1.0f;
  float u = fmaxf(f, 1.17549435e-38f);
  const float l2u = __log2f(u);                     // strictly < 0
  return fmaf(-0.69314718056f, __log2f(-l2u), 0.3665129206f);
}

// exact fp64 gumbel; u is a 23-bit dyadic rational, exact in double
__device__ __forceinline__ double gumbel64(unsigned bits) {
  float f = __uint_as_float((bits >> 9) | 0x3f800000u) - 1.0f;
  double u = (double)fmaxf(f, 1.17549435e-38f);
  return -log(-log(u));
}

// pack fp64 score (top 49 monotone bits) + 15-bit (32767-n): u64 max == (score, then smaller n)
__device__ __forceinline__ unsigned long long packcell(double v, int n) {
  unsigned long long u = (unsigned long long)__double_as_longlong(v);
  u = (u >> 63) ? ~u : (u | 0x8000000000000000ull);
  return (u & 0xFFFFFFFFFFFF8000ull) | (unsigned long long)(32767 - n);
}

// monotone fp32 pack (high 32) + gene index (low 32) for top-2 reduction
__device__ __forceinline__ unsigned long long packscreen(float v, int n) {
  unsigned u = __float_as_uint(v);
  u = (u >> 31) ? ~u : (u | 0x80000000u);
  return ((unsigned long long)u << 32) | (unsigned)n;
}

// ---------- prep: Wf=Wk@W1k (fp64 math, fp32 store), Q, qbT; c12; zero cells/bdone ----------
__global__ __launch_bounds__(128) void kprep(
    const float* __restrict__ pe, const float* __restrict__ Wq,
    const float* __restrict__ bq, const float* __restrict__ Wk,
    const float* __restrict__ bk, const float* __restrict__ W1,
    const float* __restrict__ b1, const float* __restrict__ w2,
    float* __restrict__ Wf32, double* __restrict__ qbT,
    float* __restrict__ Qm, unsigned long long* __restrict__ cells,
    double2* __restrict__ c12, int* __restrict__ bdone) {
  __shared__ float L[512];
  __shared__ double Ld[128];
  const int t = threadIdx.x;
  const int bid = blockIdx.x;
  if (bid < 256) {
    L[t] = Wk[bid * 128 + t];
    __syncthreads();
    double acc = 0.0;
    #pragma unroll 16
    for (int j = 0; j < 128; ++j)
      acc = fma((double)L[j], (double)W1[(128 + j) * 128 + t], acc);
    Wf32[bid * 128 + t] = (float)acc;
  } else if (bid < 320) {
    const int b = bid - 256;
    #pragma unroll
    for (int i = 0; i < 4; ++i) L[t + 128 * i] = pe[b * 512 + t + 128 * i];
    __syncthreads();
    double q = (double)bq[t];
    #pragma unroll 16
    for (int f = 0; f < 512; ++f)
      q = fma((double)L[f], (double)Wq[f * 128 + t], q);
    Qm[b * 128 + t] = (float)q;   // epilogue path stays fp32
    Ld[t] = q;
    __syncthreads();
    // qb[b,d=t] = Q@W1[:128] + b1 + bk@W1[128:]; store transposed qbT[d][b]
    double acc = (double)b1[t];
    #pragma unroll 8
    for (int j = 0; j < 128; ++j) {
      acc = fma(Ld[j], (double)W1[j * 128 + t], acc);
      acc = fma((double)bk[j], (double)W1[(128 + j) * 128 + t], acc);
    }
    qbT[t * 64 + b] = acc;
  } else {
    for (int i = t; i < 1280; i += 128) cells[i] = 0ull;
    if (t < 64) bdone[t] = 0;
    const double w2d = (double)w2[t];
    c12[t] = make_double2(0.55 * w2d, 0.45 * w2d);
  }
}

// ---------- ksim: kp(fp32 GEMM) + sim(fp64) -> simg[64][20000] (NO atomics) ----------
// 625 blocks x 256 thr, 32 genes/block. vs R5: each thread owns FOUR d's
// (d = 4*sl..4*sl+3, sl = lane&31) so the W LDS read is one ds_read_b128 per f
// and the gene b128 reads amortize over 2x the fma work: per 4096 fma the LDS
// cost is 256 gene-b128 + 256 W-b128 (~6144 cy) vs R5's 8704 cy per 4096 fma
// (18% issue cut). Wave wv covers genes wv*8..wv*8+7; half-wave h = lane>>5
// owns genes wv*8+4h..+3 (gene reads uniform per half -> 2-addr broadcast,
// free). Wt (32-f x 128-d tile) and kpL (32x128) OVERLAY (Wt dead before kpL
// written) -> LDS 50 KB.
// Bit-exactness: every kp[g][d] is the same single fma chain, f ascending
// 0..255, same W/ge values -> kp bit-identical to R5. Phase 2: fp64 sim, wave
// wv genes wv*8..+7, lane = batch, dd-pairs in order -> identical fp64 op
// sequence -> simg bit-identical.
__global__ __launch_bounds__(256) void ksim(
    const float* __restrict__ ge, const float* __restrict__ Wf32,
    const double* __restrict__ qbT, const double2* __restrict__ c12,
    float* __restrict__ simg) {
  __shared__ float SB[8448];    // geL [32][256] (32 KB) / simLf [64][33] (33 KB)
  __shared__ float WK[4096];    // 16 KB: Wt (phase1 tile) / kpL [32][128] (after)
  float* geL = SB;
  float* simLf = SB;
  float* Wt = WK;
  float* kpL = WK;
  const int t = threadIdx.x;
  const int wv = t >> 6;
  const int lane = t & 63;
  const int h = lane >> 5;
  const int sl = lane & 31;
  const int g0 = blockIdx.x * 32;     // 625 blocks * 32 genes

  // stage ge tile (32 genes x 256 f) -> LDS: 8 independent float4 per thread
  {
    const float4* src = (const float4*)(ge + (size_t)g0 * 256);
    float4* dst = (float4*)geL;
    #pragma unroll
    for (int i = 0; i < 8; ++i) dst[t + i * 256] = src[t + i * 256];
  }

  // ---- phase 1: fp32 GEMM, W in single-buffered 32-f LDS tiles ----
  float acc[4][4];   // [gene j][d reg]
  #pragma unroll
  for (int j = 0; j < 4; ++j)
    #pragma unroll
    for (int r = 0; r < 4; ++r) acc[j][r] = 0.f;
  const float* gL = geL + (wv * 8 + h * 4) * 256;

  for (int tile = 0; tile < 8; ++tile) {
    __syncthreads();   // tile 0: geL staged; else: prev tile's Wt reads done
    {
      const float4* wsrc = (const float4*)(Wf32 + tile * 32 * 128);
      float4* wdst = (float4*)Wt;
      #pragma unroll
      for (int i = 0; i < 4; ++i) wdst[t + i * 256] = wsrc[t + i * 256];
    }
    __syncthreads();
    #pragma unroll
    for (int fr = 0; fr < 32; fr += 4) {
      const int f0 = tile * 32 + fr;
      const float4 w0 = *(const float4*)(Wt + (fr + 0) * 128 + 4 * sl);
      const float4 w1 = *(const float4*)(Wt + (fr + 1) * 128 + 4 * sl);
      const float4 w2 = *(const float4*)(Wt + (fr + 2) * 128 + 4 * sl);
      const float4 w3 = *(const float4*)(Wt + (fr + 3) * 128 + 4 * sl);
      #pragma unroll
      for (int j = 0; j < 4; ++j) {
        const float4 gv = *(const float4*)(gL + j * 256 + f0);  // half-uniform bcast
        acc[j][0] = fmaf(gv.x, w0.x, acc[j][0]);
        acc[j][1] = fmaf(gv.x, w0.y, acc[j][1]);
        acc[j][2] = fmaf(gv.x, w0.z, acc[j][2]);
        acc[j][3] = fmaf(gv.x, w0.w, acc[j][3]);
        acc[j][0] = fmaf(gv.y, w1.x, acc[j][0]);
        acc[j][1] = fmaf(gv.y, w1.y, acc[j][1]);
        acc[j][2] = fmaf(gv.y, w1.z, acc[j][2]);
        acc[j][3] = fmaf(gv.y, w1.w, acc[j][3]);
        acc[j][0] = fmaf(gv.z, w2.x, acc[j][0]);
        acc[j][1] = fmaf(gv.z, w2.y, acc[j][1]);
        acc[j][2] = fmaf(gv.z, w2.z, acc[j][2]);
        acc[j][3] = fmaf(gv.z, w2.w, acc[j][3]);
        acc[j][0] = fmaf(gv.w, w3.x, acc[j][0]);
        acc[j][1] = fmaf(gv.w, w3.y, acc[j][1]);
        acc[j][2] = fmaf(gv.w, w3.z, acc[j][2]);
        acc[j][3] = fmaf(gv.w, w3.w, acc[j][3]);
      }
    }
  }

  __syncthreads();   // all Wt/geL phase-1 reads done (WK reused as kpL)
  #pragma unroll
  for (int j = 0; j < 4; ++j)
    *(float4*)(kpL + (wv * 8 + h * 4 + j) * 128 + 4 * sl) =
        make_float4(acc[j][0], acc[j][1], acc[j][2], acc[j][3]);
  __syncthreads();

  // ---- phase 2: fp64 sim (8 genes/wave, lane = batch) ----
  double s[8];
  #pragma unroll
  for (int j = 0; j < 8; ++j) s[j] = 0.0;
  for (int dd = 0; dd < 128; dd += 2) {
    const double2 cc0 = c12[dd];                  // uniform -> s_load
    const double2 cc1 = c12[dd + 1];
    const double qv0 = qbT[dd * 64 + lane];       // coalesced, L1-hot
    const double qv1 = qbT[(dd + 1) * 64 + lane];
    #pragma unroll
    for (int j = 0; j < 8; ++j) {
      const float2 kv = *(const float2*)(kpL + (wv * 8 + j) * 128 + dd);  // bcast
      const double tt0 = qv0 + (double)kv.x;
      s[j] = fma(tt0, cc0.x, s[j]);
      s[j] = fma(fabs(tt0), cc0.y, s[j]);
      const double tt1 = qv1 + (double)kv.y;
      s[j] = fma(tt1, cc1.x, s[j]);
      s[j] = fma(fabs(tt1), cc1.y, s[j]);
    }
  }
  #pragma unroll
  for (int j = 0; j < 8; ++j)
    simLf[lane * 33 + (wv * 8 + j)] = (float)(2.0 * s[j]);
  __syncthreads();

  // ---- transpose-store: 2 passes; thread -> b = (t>>3)+32p, chunk = t&7 ----
  #pragma unroll
  for (int p = 0; p < 2; ++p) {
    const int b = (t >> 3) + 32 * p;
    const int gc = t & 7;
    float4 v;
    v.x = simLf[b * 33 + gc * 4 + 0];
    v.y = simLf[b * 33 + gc * 4 + 1];
    v.z = simLf[b * 33 + gc * 4 + 2];
    v.w = simLf[b * 33 + gc * 4 + 3];
    *(float4*)(simg + (size_t)b * NG + g0 + gc * 4) = v;
  }
}

// ---------- kargfin: screen + last-block-per-batch fused epilogue ----------
// 2560 blocks x 256 thr. Block = (cell, window); window = 10000 genes. Screen
// identical to R5 (pairwise-ILP threefry, fp32 top-2, wave butterfly, LDS
// merge, fp64-exact winner + runner-up iff gap < 1e-4, one atomicMax/window).
// NEW: after its atomicMax, t0 does threadfence + ticket atomicAdd(bdone[b]);
// the 40th block of a batch (old==39) runs the old kfinal epilogue for b in
// this kernel (saves the 64-block latency-bound kfinal dispatch + a gap).
// Release: fence between cells-RMW and ticket-RMW. Acquire: cells read back
// via atomicMax(addr, 0) -- same-address RMW coherence; every real packed
// value > 0 so max-with-0 is a pure read.
__global__ __launch_bounds__(256) void kargfin(
    const float* __restrict__ simg, const float* __restrict__ ge,
    const float* __restrict__ Wv, const float* __restrict__ bv,
    const float* __restrict__ Qm, unsigned long long* __restrict__ cells,
    int* __restrict__ bdone, float* __restrict__ out) {
  __shared__ unsigned long long R1s[4], R2s[4];
  __shared__ int fin;
  __shared__ int nsel[20];
  __shared__ float sc[20];
  __shared__ float ctxp[4][128];
  const int cell = blockIdx.x >> 1;            // = b*20 + k
  const int wdw = blockIdx.x & 1;
  const int t = threadIdx.x;
  const int wv = t >> 6;
  const int lane = t & 63;
  const int b = (unsigned)cell / 20u;
  const float* sb = simg + (size_t)b * NG;
  const unsigned ib = (unsigned)cell * (unsigned)NG;
  const int base = wdw * 10000;
  const int end = base + 10000;

  float m1 = -3e38f, m2 = -3e38f;
  int n1 = -1, n2 = -1;
  int n = base + t;
  // pair loop: candidates n and n+256 (independent threefry chains -> ILP 2)
  for (; n + 256 < end; n += 512) {
    const unsigned bbA = tfbits(ib + (unsigned)n);
    const unsigned bbB = tfbits(ib + (unsigned)(n + 256));
    const float sA = sb[n] + gumbel32(bbA);
    const float sB = sb[n + 256] + gumbel32(bbB);
    if (sA > m1) { m2 = m1; n2 = n1; m1 = sA; n1 = n; }
    else if (sA > m2) { m2 = sA; n2 = n; }
    if (sB > m1) { m2 = m1; n2 = n1; m1 = sB; n1 = n + 256; }
    else if (sB > m2) { m2 = sB; n2 = n + 256; }
  }
  for (; n < end; n += 256) {
    const unsigned bb = tfbits(ib + (unsigned)n);
    const float sc_ = sb[n] + gumbel32(bb);
    if (sc_ > m1) { m2 = m1; n2 = n1; m1 = sc_; n1 = n; }
    else if (sc_ > m2) { m2 = sc_; n2 = n; }
  }
  unsigned long long p1 = packscreen(m1, n1);
  unsigned long long p2 = packscreen(m2, n2);
  // wave top-2 butterfly: merge sorted pairs (p1>=p2), (q1>=q2)
  #pragma unroll
  for (int off = 32; off; off >>= 1) {
    unsigned long long q1 = __shfl_xor(p1, off, 64);
    unsigned long long q2 = __shfl_xor(p2, off, 64);
    if (q1 > p1) {
      unsigned long long t1 = p1;
      p1 = q1;
      p2 = (q2 > t1) ? q2 : t1;
    } else {
      p2 = (q1 > p2) ? q1 : p2;
    }
  }
  if (lane == 0) { R1s[wv] = p1; R2s[wv] = p2; }
  __syncthreads();
  if (t == 0) {
    unsigned long long P1 = R1s[0], P2 = R2s[0];
    #pragma unroll
    for (int w = 1; w < 4; ++w) {
      unsigned long long q1 = R1s[w], q2 = R2s[w];
      if (q1 > P1) {
        unsigned long long t1 = P1;
        P1 = q1;
        P2 = (q2 > t1) ? q2 : t1;
      } else {
        P2 = (q1 > P2) ? q1 : P2;
      }
    }
    const int w1 = (int)(P1 & 0xFFFFFFFFull);
    const int w2i = (int)(P2 & 0xFFFFFFFFull);
    const unsigned bb1 = tfbits(ib + (unsigned)w1);
    const float s1f = sb[w1];
    const float sc1 = s1f + gumbel32(bb1);
    unsigned long long pb = packcell((double)s1f + gumbel64(bb1), w1);
    if (w2i >= 0) {
      const unsigned bb2 = tfbits(ib + (unsigned)w2i);
      const float s2f = sb[w2i];
      const float sc2 = s2f + gumbel32(bb2);
      if ((sc1 - sc2) < 1e-4f) {
        const unsigned long long u2 =
            packcell((double)s2f + gumbel64(bb2), w2i);
        if (u2 > pb) pb = u2;
      }
    }
    atomicMax(&cells[cell], pb);
    __threadfence();
    const int old = atomicAdd(&bdone[b], 1);
    fin = (old == 39) ? 1 : 0;
  }
  __syncthreads();
  if (!fin) return;

  // ---- fused epilogue: this block is the last of batch b's 40 blocks ----
  if (t < 20)
    nsel[t] = 32767 - (int)(atomicMax(&cells[b * 20 + t], 0ull) & 0x7FFFull);
  __syncthreads();
  const float2 qv = ((const float2*)(Qm + b * 128))[lane];
  const float2 bvv = ((const float2*)bv)[lane];
  const float* gr[5];
  float2 V[5];
  #pragma unroll
  for (int j = 0; j < 5; ++j) {
    gr[j] = ge + (size_t)nsel[wv * 5 + j] * 256;
    V[j] = bvv;
  }
  for (int f = 0; f < 256; f += 4) {
    const float2 w0 = ((const float2*)(Wv + (size_t)(f + 0) * 128))[lane];
    const float2 w1 = ((const float2*)(Wv + (size_t)(f + 1) * 128))[lane];
    const float2 w2_ = ((const float2*)(Wv + (size_t)(f + 2) * 128))[lane];
    const float2 w3 = ((const float2*)(Wv + (size_t)(f + 3) * 128))[lane];
    #pragma unroll
    for (int j = 0; j < 5; ++j) {
      const float4 gv = *(const float4*)(gr[j] + f);   // uniform -> s_load
      V[j].x = fmaf(gv.x, w0.x, V[j].x); V[j].y = fmaf(gv.x, w0.y, V[j].y);
      V[j].x = fmaf(gv.y, w1.x, V[j].x); V[j].y = fmaf(gv.y, w1.y, V[j].y);
      V[j].x = fmaf(gv.z, w2_.x, V[j].x); V[j].y = fmaf(gv.z, w2_.y, V[j].y);
      V[j].x = fmaf(gv.w, w3.x, V[j].x); V[j].y = fmaf(gv.w, w3.y, V[j].y);
    }
  }
  #pragma unroll
  for (int j = 0; j < 5; ++j) {
    float pr = qv.x * V[j].x + qv.y * V[j].y;
    #pragma unroll
    for (int off = 32; off; off >>= 1) pr += __shfl_xor(pr, off, 64);
    if (lane == 0) sc[wv * 5 + j] = pr * 0.08838834764831845f;  // 1/sqrt(128)
  }
  __syncthreads();
  float m = -3.0e38f;
  #pragma unroll
  for (int i = 0; i < 20; ++i) m = fmaxf(m, sc[i]);
  float s = 0.f;
  #pragma unroll
  for (int i = 0; i < 20; ++i) s += expf(sc[i] - m);
  const float inv = 1.0f / s;
  float c0 = 0.f, c1 = 0.f;
  #pragma unroll
  for (int j = 0; j < 5; ++j) {
    const float wk = expf(sc[wv * 5 + j] - m) * inv;
    c0 = fmaf(wk, V[j].x, c0);
    c1 = fmaf(wk, V[j].y, c1);
  }
  ctxp[wv][2 * lane] = c0;
  ctxp[wv][2 * lane + 1] = c1;
  __syncthreads();
  if (t < 128)
    out[b * 128 + t] = (ctxp[0][t] + ctxp[1][t]) + (ctxp[2][t] + ctxp[3][t]);
}

extern "C" void kernel_launch(void* const* d_in, const int* in_sizes, int n_in,
                              void* d_out, int out_size, void* d_ws, size_t ws_size,
                              hipStream_t stream) {
  (void)in_sizes; (void)n_in; (void)out_size; (void)ws_size;
  const float* pe = (const float*)d_in[0];
  const float* ge = (const float*)d_in[1];
  const float* Wq = (const float*)d_in[2];
  const float* bq = (const float*)d_in[3];
  const float* Wk = (const float*)d_in[4];
  const float* bk = (const float*)d_in[5];
  const float* Wv = (const float*)d_in[6];
  const float* bvp = (const float*)d_in[7];
  const float* W1 = (const float*)d_in[8];
  const float* b1 = (const float*)d_in[9];
  const float* w2 = (const float*)d_in[10];
  // d_in[11] = b2: uniform over n -> cancels in argmax; absent from output path.

  char* w = (char*)d_ws;
  float* Wf32 = (float*)w;                               // 131072 B
  double* qbT = (double*)(w + 131072);                   // 65536 B
  float* Qm = (float*)(w + 196608);                      // 32768 B
  unsigned long long* cells =
      (unsigned long long*)(w + 229376);                 // 10240 B
  double2* c12 = (double2*)(w + 239616);                 // 2048 B
  int* bdone = (int*)(w + 241664);                       // 256 B
  float* simg = (float*)(w + 262144);                    // 5,120,000 B (~5.4 MB total)
  float* out = (float*)d_out;

  kprep<<<dim3(321), dim3(128), 0, stream>>>(pe, Wq, bq, Wk, bk, W1, b1, w2,
                                             Wf32, qbT, Qm, cells, c12, bdone);
  ksim<<<dim3(625), dim3(256), 0, stream>>>(ge, Wf32, qbT, c12, simg);
  kargfin<<<dim3(2560), dim3(256), 0, stream>>>(simg, ge, Wv, bvp, Qm, cells,
                                                bdone, out);
}

// Round 7
// 265.314 us; speedup vs baseline: 1.1980x; 1.1980x over previous
//
#include <hip/hip_runtime.h>

#define NG 20000

// single-instruction rotate (v_alignbit_b32): rotl(x,r) == alignbit(x,x,32-r)
__device__ __forceinline__ unsigned rotl32(unsigned x, int r) {
  return __builtin_amdgcn_alignbit(x, x, 32 - r);
}

// ---------- JAX threefry2x32, key = (0, 42) ----------
__device__ __forceinline__ void threefry2x32(unsigned x0, unsigned x1,
                                             unsigned& o0, unsigned& o1) {
  const unsigned ks0 = 0u;
  const unsigned ks1 = 42u;
  const unsigned ks2 = 0x1BD11BDAu ^ 0u ^ 42u;
  x0 += ks0; x1 += ks1;
#define TFR(r) { x0 += x1; x1 = rotl32(x1, (r)); x1 ^= x0; }
  TFR(13) TFR(15) TFR(26) TFR(6)
  x0 += ks1; x1 += ks2 + 1u;
  TFR(17) TFR(29) TFR(16) TFR(24)
  x0 += ks2; x1 += ks0 + 2u;
  TFR(13) TFR(15) TFR(26) TFR(6)
  x0 += ks0; x1 += ks1 + 3u;
  TFR(17) TFR(29) TFR(16) TFR(24)
  x0 += ks1; x1 += ks2 + 4u;
  TFR(13) TFR(15) TFR(26) TFR(6)
  x0 += ks2; x1 += ks0 + 5u;
#undef TFR
  o0 = x0; o1 = x1;
}

// JAX threefry_partitionable: bits(i) = o0 ^ o1 of threefry((0,42),(0,i))
__device__ __forceinline__ unsigned tfbits(unsigned ctr) {
  unsigned o0, o1;
  threefry2x32(0u, ctr, o0, o1);
  return o0 ^ o1;
}

// fp32 fast-screen gumbel, constant-folded: g = -ln2*log2(-log2(u)) - ln(ln2)
__device__ __forceinline__ float gumbel32(unsigned bits) {
  float f = __uint_as_float((bits >> 9) | 0x3f800000u) - 1.0f;
  float u = fmaxf(f, 1.17549435e-38f);
  const float l2u = __log2f(u);                     // strictly < 0
  return fmaf(-0.69314718056f, __log2f(-l2u), 0.3665129206f);
}

// exact fp64 gumbel; u is a 23-bit dyadic rational, exact in double
__device__ __forceinline__ double gumbel64(unsigned bits) {
  float f = __uint_as_float((bits >> 9) | 0x3f800000u) - 1.0f;
  double u = (double)fmaxf(f, 1.17549435e-38f);
  return -log(-log(u));
}

// pack fp64 score (top 49 monotone bits) + 15-bit (32767-n): u64 max == (score, then smaller n)
__device__ __forceinline__ unsigned long long packcell(double v, int n) {
  unsigned long long u = (unsigned long long)__double_as_longlong(v);
  u = (u >> 63) ? ~u : (u | 0x8000000000000000ull);
  return (u & 0xFFFFFFFFFFFF8000ull) | (unsigned long long)(32767 - n);
}

// monotone fp32 pack (high 32) + gene index (low 32) for top-2 reduction
__device__ __forceinline__ unsigned long long packscreen(float v, int n) {
  unsigned u = __float_as_uint(v);
  u = (u >> 31) ? ~u : (u | 0x80000000u);
  return ((unsigned long long)u << 32) | (unsigned)n;
}

// ---------- prep: Wf=Wk@W1k (fp64 math, fp32 store), Q, qbT; c12; zero cells ----------
__global__ __launch_bounds__(128) void kprep(
    const float* __restrict__ pe, const float* __restrict__ Wq,
    const float* __restrict__ bq, const float* __restrict__ Wk,
    const float* __restrict__ bk, const float* __restrict__ W1,
    const float* __restrict__ b1, const float* __restrict__ w2,
    float* __restrict__ Wf32, double* __restrict__ qbT,
    float* __restrict__ Qm, unsigned long long* __restrict__ cells,
    double2* __restrict__ c12) {
  __shared__ float L[512];
  __shared__ double Ld[128];
  const int t = threadIdx.x;
  const int bid = blockIdx.x;
  if (bid < 256) {
    L[t] = Wk[bid * 128 + t];
    __syncthreads();
    double acc = 0.0;
    #pragma unroll 16
    for (int j = 0; j < 128; ++j)
      acc = fma((double)L[j], (double)W1[(128 + j) * 128 + t], acc);
    Wf32[bid * 128 + t] = (float)acc;
  } else if (bid < 320) {
    const int b = bid - 256;
    #pragma unroll
    for (int i = 0; i < 4; ++i) L[t + 128 * i] = pe[b * 512 + t + 128 * i];
    __syncthreads();
    double q = (double)bq[t];
    #pragma unroll 16
    for (int f = 0; f < 512; ++f)
      q = fma((double)L[f], (double)Wq[f * 128 + t], q);
    Qm[b * 128 + t] = (float)q;   // epilogue path stays fp32
    Ld[t] = q;
    __syncthreads();
    // qb[b,d=t] = Q@W1[:128] + b1 + bk@W1[128:]; store transposed qbT[d][b]
    double acc = (double)b1[t];
    #pragma unroll 8
    for (int j = 0; j < 128; ++j) {
      acc = fma(Ld[j], (double)W1[j * 128 + t], acc);
      acc = fma((double)bk[j], (double)W1[(128 + j) * 128 + t], acc);
    }
    qbT[t * 64 + b] = acc;
  } else {
    for (int i = t; i < 1280; i += 128) cells[i] = 0ull;
    const double w2d = (double)w2[t];
    c12[t] = make_double2(0.55 * w2d, 0.45 * w2d);
  }
}

// ---------- ksim: kp(fp32 GEMM) + sim(fp64) -> simg[64][20000] (NO atomics) ----------
// 625 blocks x 256 thr, 32 genes/block (R6 version, verified bit-exact).
// Each thread owns FOUR d's (d = 4*sl..4*sl+3, sl = lane&31): W LDS read is one
// ds_read_b128 per f and gene b128 reads amortize over 2x the fma work (~18%
// issue cut vs R5; ledger-measured ksim ~59 -> ~37 us in R6). Wave wv covers
// genes wv*8..wv*8+7; half-wave h = lane>>5 owns genes wv*8+4h..+3. Wt and kpL
// overlay (Wt dead before kpL written) -> LDS 50 KB.
// Bit-exactness: every kp[g][d] is the same single fma chain, f ascending
// 0..255, same W/ge values. Phase 2 fp64 op sequence identical -> simg
// bit-identical.
__global__ __launch_bounds__(256) void ksim(
    const float* __restrict__ ge, const float* __restrict__ Wf32,
    const double* __restrict__ qbT, const double2* __restrict__ c12,
    float* __restrict__ simg) {
  __shared__ float SB[8448];    // geL [32][256] (32 KB) / simLf [64][33] (33 KB)
  __shared__ float WK[4096];    // 16 KB: Wt (phase1 tile) / kpL [32][128] (after)
  float* geL = SB;
  float* simLf = SB;
  float* Wt = WK;
  float* kpL = WK;
  const int t = threadIdx.x;
  const int wv = t >> 6;
  const int lane = t & 63;
  const int h = lane >> 5;
  const int sl = lane & 31;
  const int g0 = blockIdx.x * 32;     // 625 blocks * 32 genes

  // stage ge tile (32 genes x 256 f) -> LDS: 8 independent float4 per thread
  {
    const float4* src = (const float4*)(ge + (size_t)g0 * 256);
    float4* dst = (float4*)geL;
    #pragma unroll
    for (int i = 0; i < 8; ++i) dst[t + i * 256] = src[t + i * 256];
  }

  // ---- phase 1: fp32 GEMM, W in single-buffered 32-f LDS tiles ----
  float acc[4][4];   // [gene j][d reg]
  #pragma unroll
  for (int j = 0; j < 4; ++j)
    #pragma unroll
    for (int r = 0; r < 4; ++r) acc[j][r] = 0.f;
  const float* gL = geL + (wv * 8 + h * 4) * 256;

  for (int tile = 0; tile < 8; ++tile) {
    __syncthreads();   // tile 0: geL staged; else: prev tile's Wt reads done
    {
      const float4* wsrc = (const float4*)(Wf32 + tile * 32 * 128);
      float4* wdst = (float4*)Wt;
      #pragma unroll
      for (int i = 0; i < 4; ++i) wdst[t + i * 256] = wsrc[t + i * 256];
    }
    __syncthreads();
    #pragma unroll
    for (int fr = 0; fr < 32; fr += 4) {
      const int f0 = tile * 32 + fr;
      const float4 w0 = *(const float4*)(Wt + (fr + 0) * 128 + 4 * sl);
      const float4 w1 = *(const float4*)(Wt + (fr + 1) * 128 + 4 * sl);
      const float4 w2 = *(const float4*)(Wt + (fr + 2) * 128 + 4 * sl);
      const float4 w3 = *(const float4*)(Wt + (fr + 3) * 128 + 4 * sl);
      #pragma unroll
      for (int j = 0; j < 4; ++j) {
        const float4 gv = *(const float4*)(gL + j * 256 + f0);  // half-uniform bcast
        acc[j][0] = fmaf(gv.x, w0.x, acc[j][0]);
        acc[j][1] = fmaf(gv.x, w0.y, acc[j][1]);
        acc[j][2] = fmaf(gv.x, w0.z, acc[j][2]);
        acc[j][3] = fmaf(gv.x, w0.w, acc[j][3]);
        acc[j][0] = fmaf(gv.y, w1.x, acc[j][0]);
        acc[j][1] = fmaf(gv.y, w1.y, acc[j][1]);
        acc[j][2] = fmaf(gv.y, w1.z, acc[j][2]);
        acc[j][3] = fmaf(gv.y, w1.w, acc[j][3]);
        acc[j][0] = fmaf(gv.z, w2.x, acc[j][0]);
        acc[j][1] = fmaf(gv.z, w2.y, acc[j][1]);
        acc[j][2] = fmaf(gv.z, w2.z, acc[j][2]);
        acc[j][3] = fmaf(gv.z, w2.w, acc[j][3]);
        acc[j][0] = fmaf(gv.w, w3.x, acc[j][0]);
        acc[j][1] = fmaf(gv.w, w3.y, acc[j][1]);
        acc[j][2] = fmaf(gv.w, w3.z, acc[j][2]);
        acc[j][3] = fmaf(gv.w, w3.w, acc[j][3]);
      }
    }
  }

  __syncthreads();   // all Wt/geL phase-1 reads done (WK reused as kpL)
  #pragma unroll
  for (int j = 0; j < 4; ++j)
    *(float4*)(kpL + (wv * 8 + h * 4 + j) * 128 + 4 * sl) =
        make_float4(acc[j][0], acc[j][1], acc[j][2], acc[j][3]);
  __syncthreads();

  // ---- phase 2: fp64 sim (8 genes/wave, lane = batch) ----
  double s[8];
  #pragma unroll
  for (int j = 0; j < 8; ++j) s[j] = 0.0;
  for (int dd = 0; dd < 128; dd += 2) {
    const double2 cc0 = c12[dd];                  // uniform -> s_load
    const double2 cc1 = c12[dd + 1];
    const double qv0 = qbT[dd * 64 + lane];       // coalesced, L1-hot
    const double qv1 = qbT[(dd + 1) * 64 + lane];
    #pragma unroll
    for (int j = 0; j < 8; ++j) {
      const float2 kv = *(const float2*)(kpL + (wv * 8 + j) * 128 + dd);  // bcast
      const double tt0 = qv0 + (double)kv.x;
      s[j] = fma(tt0, cc0.x, s[j]);
      s[j] = fma(fabs(tt0), cc0.y, s[j]);
      const double tt1 = qv1 + (double)kv.y;
      s[j] = fma(tt1, cc1.x, s[j]);
      s[j] = fma(fabs(tt1), cc1.y, s[j]);
    }
  }
  #pragma unroll
  for (int j = 0; j < 8; ++j)
    simLf[lane * 33 + (wv * 8 + j)] = (float)(2.0 * s[j]);
  __syncthreads();

  // ---- transpose-store: 2 passes; thread -> b = (t>>3)+32p, chunk = t&7 ----
  #pragma unroll
  for (int p = 0; p < 2; ++p) {
    const int b = (t >> 3) + 32 * p;
    const int gc = t & 7;
    float4 v;
    v.x = simLf[b * 33 + gc * 4 + 0];
    v.y = simLf[b * 33 + gc * 4 + 1];
    v.z = simLf[b * 33 + gc * 4 + 2];
    v.w = simLf[b * 33 + gc * 4 + 3];
    *(float4*)(simg + (size_t)b * NG + g0 + gc * 4) = v;
  }
}

// ---------- kargmax: 2 windows per cell, pairwise-ILP screen, atomicMax merge ----------
// R5 version (82 us, VALUBusy 90%, 16 VGPR) — fire-and-forget atomic, NO fence,
// NO fused epilogue (R6 fusion diluted occupancy 56->26% and cost +96 us).
// 2560 blocks x 256 thr. Block = (cell, window); window = 10000 genes.
// fp32 top-2 per thread (pairwise threefry ILP-2); packed-u64 top-2 wave
// butterfly; cross-wave LDS merge; thread 0 fp64-exact window winner
// (+ runner-up iff fp32 gap < 1e-4, screen err 2e-5 << margin) -> ONE atomicMax
// per window (2 writers/cell: contention-free; cells zeroed by kprep).
// Max of exact window winners == exact global argmax (window-size-independent).
__global__ __launch_bounds__(256) void kargmax(
    const float* __restrict__ simg, unsigned long long* __restrict__ cells) {
  __shared__ unsigned long long R1s[4], R2s[4];
  const int cell = blockIdx.x >> 1;            // = b*20 + k
  const int wdw = blockIdx.x & 1;
  const int t = threadIdx.x;
  const int wv = t >> 6;
  const int lane = t & 63;
  const int b = (unsigned)cell / 20u;
  const float* sb = simg + (size_t)b * NG;
  const unsigned ib = (unsigned)cell * (unsigned)NG;
  const int base = wdw * 10000;
  const int end = base + 10000;

  float m1 = -3e38f, m2 = -3e38f;
  int n1 = -1, n2 = -1;
  int n = base + t;
  // pair loop: candidates n and n+256 (independent threefry chains -> ILP 2)
  for (; n + 256 < end; n += 512) {
    const unsigned bbA = tfbits(ib + (unsigned)n);
    const unsigned bbB = tfbits(ib + (unsigned)(n + 256));
    const float sA = sb[n] + gumbel32(bbA);
    const float sB = sb[n + 256] + gumbel32(bbB);
    if (sA > m1) { m2 = m1; n2 = n1; m1 = sA; n1 = n; }
    else if (sA > m2) { m2 = sA; n2 = n; }
    if (sB > m1) { m2 = m1; n2 = n1; m1 = sB; n1 = n + 256; }
    else if (sB > m2) { m2 = sB; n2 = n + 256; }
  }
  for (; n < end; n += 256) {
    const unsigned bb = tfbits(ib + (unsigned)n);
    const float sc = sb[n] + gumbel32(bb);
    if (sc > m1) { m2 = m1; n2 = n1; m1 = sc; n1 = n; }
    else if (sc > m2) { m2 = sc; n2 = n; }
  }
  unsigned long long p1 = packscreen(m1, n1);
  unsigned long long p2 = packscreen(m2, n2);
  // wave top-2 butterfly: merge sorted pairs (p1>=p2), (q1>=q2)
  #pragma unroll
  for (int off = 32; off; off >>= 1) {
    unsigned long long q1 = __shfl_xor(p1, off, 64);
    unsigned long long q2 = __shfl_xor(p2, off, 64);
    if (q1 > p1) {
      unsigned long long t1 = p1;
      p1 = q1;
      p2 = (q2 > t1) ? q2 : t1;
    } else {
      p2 = (q1 > p2) ? q1 : p2;
    }
  }
  if (lane == 0) { R1s[wv] = p1; R2s[wv] = p2; }
  __syncthreads();
  if (t == 0) {
    unsigned long long P1 = R1s[0], P2 = R2s[0];
    #pragma unroll
    for (int w = 1; w < 4; ++w) {
      unsigned long long q1 = R1s[w], q2 = R2s[w];
      if (q1 > P1) {
        unsigned long long t1 = P1;
        P1 = q1;
        P2 = (q2 > t1) ? q2 : t1;
      } else {
        P2 = (q1 > P2) ? q1 : P2;
      }
    }
    const int w1 = (int)(P1 & 0xFFFFFFFFull);
    const int w2i = (int)(P2 & 0xFFFFFFFFull);
    const unsigned bb1 = tfbits(ib + (unsigned)w1);
    const float s1f = sb[w1];
    const float sc1 = s1f + gumbel32(bb1);
    unsigned long long pb = packcell((double)s1f + gumbel64(bb1), w1);
    if (w2i >= 0) {
      const unsigned bb2 = tfbits(ib + (unsigned)w2i);
      const float s2f = sb[w2i];
      const float sc2 = s2f + gumbel32(bb2);
      if ((sc1 - sc2) < 1e-4f) {
        const unsigned long long u2 =
            packcell((double)s2f + gumbel64(bb2), w2i);
        if (u2 > pb) pb = u2;
      }
    }
    atomicMax(&cells[cell], pb);
  }
}

// ---------- epilogue (fp32): 5 interleaved V-GEMVs per wave, softmax over K, context ----------
__global__ __launch_bounds__(256) void kfinal(
    const float* __restrict__ ge, const float* __restrict__ Wv,
    const float* __restrict__ bv, const float* __restrict__ Qm,
    const unsigned long long* __restrict__ cells, float* __restrict__ out) {
  const int b = blockIdx.x;
  const int t = threadIdx.x;
  const int wv = t >> 6;
  const int lane = t & 63;
  __shared__ float sc[20];
  __shared__ float ctxp[4][128];
  const float2 qv = ((const float2*)(Qm + b * 128))[lane];
  const float2 bvv = ((const float2*)bv)[lane];
  const float* gr[5];
  float2 V[5];
  #pragma unroll
  for (int j = 0; j < 5; ++j) {
    const unsigned long long cell = cells[b * 20 + wv * 5 + j];
    const int n = 32767 - (int)(cell & 0x7FFFull);
    gr[j] = ge + (size_t)n * 256;
    V[j] = bvv;
  }
  for (int f = 0; f < 256; f += 4) {
    const float2 w0 = ((const float2*)(Wv + (size_t)(f + 0) * 128))[lane];
    const float2 w1 = ((const float2*)(Wv + (size_t)(f + 1) * 128))[lane];
    const float2 w2_ = ((const float2*)(Wv + (size_t)(f + 2) * 128))[lane];
    const float2 w3 = ((const float2*)(Wv + (size_t)(f + 3) * 128))[lane];
    #pragma unroll
    for (int j = 0; j < 5; ++j) {
      const float4 gv = *(const float4*)(gr[j] + f);   // uniform -> s_load
      V[j].x = fmaf(gv.x, w0.x, V[j].x); V[j].y = fmaf(gv.x, w0.y, V[j].y);
      V[j].x = fmaf(gv.y, w1.x, V[j].x); V[j].y = fmaf(gv.y, w1.y, V[j].y);
      V[j].x = fmaf(gv.z, w2_.x, V[j].x); V[j].y = fmaf(gv.z, w2_.y, V[j].y);
      V[j].x = fmaf(gv.w, w3.x, V[j].x); V[j].y = fmaf(gv.w, w3.y, V[j].y);
    }
  }
  #pragma unroll
  for (int j = 0; j < 5; ++j) {
    float pr = qv.x * V[j].x + qv.y * V[j].y;
    #pragma unroll
    for (int off = 32; off; off >>= 1) pr += __shfl_xor(pr, off, 64);
    if (lane == 0) sc[wv * 5 + j] = pr * 0.08838834764831845f;  // 1/sqrt(128)
  }
  __syncthreads();
  float m = -3.0e38f;
  #pragma unroll
  for (int i = 0; i < 20; ++i) m = fmaxf(m, sc[i]);
  float s = 0.f;
  #pragma unroll
  for (int i = 0; i < 20; ++i) s += expf(sc[i] - m);
  const float inv = 1.0f / s;
  float c0 = 0.f, c1 = 0.f;
  #pragma unroll
  for (int j = 0; j < 5; ++j) {
    const float wk = expf(sc[wv * 5 + j] - m) * inv;
    c0 = fmaf(wk, V[j].x, c0);
    c1 = fmaf(wk, V[j].y, c1);
  }
  ctxp[wv][2 * lane] = c0;
  ctxp[wv][2 * lane + 1] = c1;
  __syncthreads();
  if (t < 128)
    out[b * 128 + t] = (ctxp[0][t] + ctxp[1][t]) + (ctxp[2][t] + ctxp[3][t]);
}

extern "C" void kernel_launch(void* const* d_in, const int* in_sizes, int n_in,
                              void* d_out, int out_size, void* d_ws, size_t ws_size,
                              hipStream_t stream) {
  (void)in_sizes; (void)n_in; (void)out_size; (void)ws_size;
  const float* pe = (const float*)d_in[0];
  const float* ge = (const float*)d_in[1];
  const float* Wq = (const float*)d_in[2];
  const float* bq = (const float*)d_in[3];
  const float* Wk = (const float*)d_in[4];
  const float* bk = (const float*)d_in[5];
  const float* Wv = (const float*)d_in[6];
  const float* bvp = (const float*)d_in[7];
  const float* W1 = (const float*)d_in[8];
  const float* b1 = (const float*)d_in[9];
  const float* w2 = (const float*)d_in[10];
  // d_in[11] = b2: uniform over n -> cancels in argmax; absent from output path.

  char* w = (char*)d_ws;
  float* Wf32 = (float*)w;                               // 131072 B
  double* qbT = (double*)(w + 131072);                   // 65536 B
  float* Qm = (float*)(w + 196608);                      // 32768 B
  unsigned long long* cells =
      (unsigned long long*)(w + 229376);                 // 10240 B
  double2* c12 = (double2*)(w + 239616);                 // 2048 B
  float* simg = (float*)(w + 262144);                    // 5,120,000 B (~5.4 MB total)
  float* out = (float*)d_out;

  kprep<<<dim3(321), dim3(128), 0, stream>>>(pe, Wq, bq, Wk, bk, W1, b1, w2,
                                             Wf32, qbT, Qm, cells, c12);
  ksim<<<dim3(625), dim3(256), 0, stream>>>(ge, Wf32, qbT, c12, simg);
  kargmax<<<dim3(2560), dim3(256), 0, stream>>>(simg, cells);
  kfinal<<<dim3(64), dim3(256), 0, stream>>>(ge, Wv, bvp, Qm, cells, out);
}

// Round 8
// 260.825 us; speedup vs baseline: 1.2187x; 1.0172x over previous
//
#include <hip/hip_runtime.h>

#define NG 20000

// single-instruction rotate (v_alignbit_b32): rotl(x,r) == alignbit(x,x,32-r)
__device__ __forceinline__ unsigned rotl32(unsigned x, int r) {
  return __builtin_amdgcn_alignbit(x, x, 32 - r);
}

// ---------- JAX threefry2x32, key = (0, 42) ----------
__device__ __forceinline__ void threefry2x32(unsigned x0, unsigned x1,
                                             unsigned& o0, unsigned& o1) {
  const unsigned ks0 = 0u;
  const unsigned ks1 = 42u;
  const unsigned ks2 = 0x1BD11BDAu ^ 0u ^ 42u;
  x0 += ks0; x1 += ks1;
#define TFR(r) { x0 += x1; x1 = rotl32(x1, (r)); x1 ^= x0; }
  TFR(13) TFR(15) TFR(26) TFR(6)
  x0 += ks1; x1 += ks2 + 1u;
  TFR(17) TFR(29) TFR(16) TFR(24)
  x0 += ks2; x1 += ks0 + 2u;
  TFR(13) TFR(15) TFR(26) TFR(6)
  x0 += ks0; x1 += ks1 + 3u;
  TFR(17) TFR(29) TFR(16) TFR(24)
  x0 += ks1; x1 += ks2 + 4u;
  TFR(13) TFR(15) TFR(26) TFR(6)
  x0 += ks2; x1 += ks0 + 5u;
#undef TFR
  o0 = x0; o1 = x1;
}

// JAX threefry_partitionable: bits(i) = o0 ^ o1 of threefry((0,42),(0,i))
__device__ __forceinline__ unsigned tfbits(unsigned ctr) {
  unsigned o0, o1;
  threefry2x32(0u, ctr, o0, o1);
  return o0 ^ o1;
}

// fp32 fast-screen gumbel, constant-folded: g = -ln2*log2(-log2(u)) - ln(ln2)
__device__ __forceinline__ float gumbel32(unsigned bits) {
  float f = __uint_as_float((bits >> 9) | 0x3f800000u) - 1.0f;
  float u = fmaxf(f, 1.17549435e-38f);
  const float l2u = __log2f(u);                     // strictly < 0
  return fmaf(-0.69314718056f, __log2f(-l2u), 0.3665129206f);
}

// exact fp64 gumbel; u is a 23-bit dyadic rational, exact in double
__device__ __forceinline__ double gumbel64(unsigned bits) {
  float f = __uint_as_float((bits >> 9) | 0x3f800000u) - 1.0f;
  double u = (double)fmaxf(f, 1.17549435e-38f);
  return -log(-log(u));
}

// pack fp64 score (top 49 monotone bits) + 15-bit (32767-n): u64 max == (score, then smaller n)
__device__ __forceinline__ unsigned long long packcell(double v, int n) {
  unsigned long long u = (unsigned long long)__double_as_longlong(v);
  u = (u >> 63) ? ~u : (u | 0x8000000000000000ull);
  return (u & 0xFFFFFFFFFFFF8000ull) | (unsigned long long)(32767 - n);
}

// monotone fp32 pack (high 32) + gene index (low 32) for top-2 reduction
__device__ __forceinline__ unsigned long long packscreen(float v, int n) {
  unsigned u = __float_as_uint(v);
  u = (u >> 31) ? ~u : (u | 0x80000000u);
  return ((unsigned long long)u << 32) | (unsigned)n;
}

// ---------- prep: Wf=Wk@W1k (fp64 math, fp32 store), Q, qbT; c12; zero cells ----------
__global__ __launch_bounds__(128) void kprep(
    const float* __restrict__ pe, const float* __restrict__ Wq,
    const float* __restrict__ bq, const float* __restrict__ Wk,
    const float* __restrict__ bk, const float* __restrict__ W1,
    const float* __restrict__ b1, const float* __restrict__ w2,
    float* __restrict__ Wf32, double* __restrict__ qbT,
    float* __restrict__ Qm, unsigned long long* __restrict__ cells,
    double2* __restrict__ c12) {
  __shared__ float L[512];
  __shared__ double Ld[128];
  const int t = threadIdx.x;
  const int bid = blockIdx.x;
  if (bid < 256) {
    L[t] = Wk[bid * 128 + t];
    __syncthreads();
    double acc = 0.0;
    #pragma unroll 16
    for (int j = 0; j < 128; ++j)
      acc = fma((double)L[j], (double)W1[(128 + j) * 128 + t], acc);
    Wf32[bid * 128 + t] = (float)acc;
  } else if (bid < 320) {
    const int b = bid - 256;
    #pragma unroll
    for (int i = 0; i < 4; ++i) L[t + 128 * i] = pe[b * 512 + t + 128 * i];
    __syncthreads();
    double q = (double)bq[t];
    #pragma unroll 16
    for (int f = 0; f < 512; ++f)
      q = fma((double)L[f], (double)Wq[f * 128 + t], q);
    Qm[b * 128 + t] = (float)q;   // epilogue path stays fp32
    Ld[t] = q;
    __syncthreads();
    // qb[b,d=t] = Q@W1[:128] + b1 + bk@W1[128:]; store transposed qbT[d][b]
    double acc = (double)b1[t];
    #pragma unroll 8
    for (int j = 0; j < 128; ++j) {
      acc = fma(Ld[j], (double)W1[j * 128 + t], acc);
      acc = fma((double)bk[j], (double)W1[(128 + j) * 128 + t], acc);
    }
    qbT[t * 64 + b] = acc;
  } else {
    for (int i = t; i < 1280; i += 128) cells[i] = 0ull;
    const double w2d = (double)w2[t];
    c12[t] = make_double2(0.55 * w2d, 0.45 * w2d);
  }
}

// ---------- ksim: kp(fp32 GEMM) + sim(fp64) -> simg[64][20000] (NO atomics) ----------
// R5 version (ledger-best: R5 total 259.7 vs R7 265.3 with only ksim differing;
// the 625-block 32-gene v3 lost its issue gain to occupancy: 2.44 blocks/CU
// supply + 3-block LDS cap vs v2's 4 blocks/CU at 1250 blocks).
// 1250 blocks x 256 thr, 16 genes/block. Phase 1: W staged in cooperative 32-f
// LDS tiles (16 KB, 8 tiles, single-buffered): block reads each Wf32 element
// once from L2. Wave wv owns genes wv*4..wv*4+3; thread owns d = {2*lane,
// 2*lane+1}; per-acc fma order f-ascending -> kp bit-identical. Wt reads:
// bank = 2*lane mod 32 -> 2-way conflict = free. Gene reads: wave-uniform
// addr -> LDS broadcast.
// Phase 2: fp64 sim, wave wv computes genes {wv,wv+4,wv+8,wv+12}, lane =
// batch; identical fp64 op order. Then transpose simLf via LDS, coalesced
// float4 store.
__global__ __launch_bounds__(256) void ksim(
    const float* __restrict__ ge, const float* __restrict__ Wf32,
    const double* __restrict__ qbT, const double2* __restrict__ c12,
    float* __restrict__ simg) {
  __shared__ double SBd[2048];   // 16 KB: phase1 geL; phase2 simLf [64][17]
  __shared__ float Wt[4096];     // 16 KB: one 32-f x 128-d W tile
  __shared__ float kpL[2048];    // 8 KB: kp[16][128]
  float* geL = (float*)SBd;
  float* simLf = (float*)SBd;
  const int t = threadIdx.x;
  const int wv = t >> 6;
  const int lane = t & 63;
  const int g0 = blockIdx.x * 16;     // 1250 blocks * 16 genes

  // stage ge tile (16 genes x 256 f) -> LDS: 4 independent float4 per thread
  // (ordered before first compute by the first in-loop barrier)
  {
    const float4* src = (const float4*)(ge + (size_t)g0 * 256);
    float4* dst = (float4*)geL;
    #pragma unroll
    for (int i = 0; i < 4; ++i) dst[t + i * 256] = src[t + i * 256];
  }

  // ---- phase 1: fp32 GEMM, W in single-buffered 32-f LDS tiles ----
  float acc[4][2];
  #pragma unroll
  for (int j = 0; j < 4; ++j) { acc[j][0] = 0.f; acc[j][1] = 0.f; }
  const float* gL = geL + wv * 4 * 256;

  for (int tile = 0; tile < 8; ++tile) {
    __syncthreads();   // tile 0: geL staged; else: prev tile's Wt reads done
    {
      const float4* wsrc = (const float4*)(Wf32 + tile * 32 * 128);
      float4* wdst = (float4*)Wt;
      #pragma unroll
      for (int i = 0; i < 4; ++i) wdst[t + i * 256] = wsrc[t + i * 256];
    }
    __syncthreads();
    #pragma unroll
    for (int fr = 0; fr < 32; fr += 4) {
      const int f0 = tile * 32 + fr;
      const float2 w0 = *(const float2*)(Wt + (fr + 0) * 128 + 2 * lane);
      const float2 w1 = *(const float2*)(Wt + (fr + 1) * 128 + 2 * lane);
      const float2 w2 = *(const float2*)(Wt + (fr + 2) * 128 + 2 * lane);
      const float2 w3 = *(const float2*)(Wt + (fr + 3) * 128 + 2 * lane);
      #pragma unroll
      for (int j = 0; j < 4; ++j) {
        const float4 gv = *(const float4*)(gL + j * 256 + f0);  // LDS broadcast
        acc[j][0] = fmaf(gv.x, w0.x, acc[j][0]);
        acc[j][1] = fmaf(gv.x, w0.y, acc[j][1]);
        acc[j][0] = fmaf(gv.y, w1.x, acc[j][0]);
        acc[j][1] = fmaf(gv.y, w1.y, acc[j][1]);
        acc[j][0] = fmaf(gv.z, w2.x, acc[j][0]);
        acc[j][1] = fmaf(gv.z, w2.y, acc[j][1]);
        acc[j][0] = fmaf(gv.w, w3.x, acc[j][0]);
        acc[j][1] = fmaf(gv.w, w3.y, acc[j][1]);
      }
    }
  }

  __syncthreads();   // geL reads done (SBd about to be reused as simLf)
  #pragma unroll
  for (int j = 0; j < 4; ++j)
    ((float2*)(kpL + (wv * 4 + j) * 128))[lane] =
        make_float2(acc[j][0], acc[j][1]);
  __syncthreads();

  // ---- phase 2: fp64 sim (4 genes/wave, lane = batch) ----
  double s[4];
  #pragma unroll
  for (int j = 0; j < 4; ++j) s[j] = 0.0;
  for (int dd = 0; dd < 128; ++dd) {
    const double2 cc = c12[dd];                   // uniform -> s_load
    const double qv = qbT[dd * 64 + lane];        // coalesced, L1-hot
    #pragma unroll
    for (int j = 0; j < 4; ++j) {
      const double kv = (double)kpL[(wv + j * 4) * 128 + dd];  // broadcast
      const double tt = qv + kv;
      s[j] = fma(tt, cc.x, s[j]);
      s[j] = fma(fabs(tt), cc.y, s[j]);
    }
  }
  #pragma unroll
  for (int j = 0; j < 4; ++j)
    simLf[lane * 17 + (wv + j * 4)] = (float)(2.0 * s[j]);
  __syncthreads();

  // ---- transpose-store: thread t -> b = t>>2, gene-chunk = t&3 (float4) ----
  {
    const int b = t >> 2;
    const int gc = t & 3;
    float4 v;
    v.x = simLf[b * 17 + gc * 4 + 0];
    v.y = simLf[b * 17 + gc * 4 + 1];
    v.z = simLf[b * 17 + gc * 4 + 2];
    v.w = simLf[b * 17 + gc * 4 + 3];
    *(float4*)(simg + (size_t)b * NG + g0 + gc * 4) = v;
  }
}

// ---------- kargmax: 2 windows per cell, float4-chunk ILP-4 screen, atomicMax merge ----------
// 2560 blocks x 256 thr. Block = (cell, window); window = 10000 genes = 2500
// 4-gene chunks. Thread t scans chunks c = t, t+256, ... : ONE coalesced
// float4 sim load per 4 evals (was 4 scalar loads) and FOUR independent
// threefry chains in flight (ILP-4 vs 2), loop overhead per eval halved.
// Same candidate set, same per-thread fp32 top-2 -> packed-u64 wave butterfly
// -> cross-wave LDS merge -> thread 0 fp64-exact window winner (+ runner-up
// iff fp32 gap < 1e-4, screen err 2e-5 << margin) -> ONE atomicMax per window
// (2 writers/cell: contention-free; cells zeroed by kprep). Max of exact
// window winners == exact global argmax (window-size-independent).
__global__ __launch_bounds__(256) void kargmax(
    const float* __restrict__ simg, unsigned long long* __restrict__ cells) {
  __shared__ unsigned long long R1s[4], R2s[4];
  const int cell = blockIdx.x >> 1;            // = b*20 + k
  const int wdw = blockIdx.x & 1;
  const int t = threadIdx.x;
  const int wv = t >> 6;
  const int lane = t & 63;
  const int b = (unsigned)cell / 20u;
  const float* sb = simg + (size_t)b * NG;
  const unsigned ib = (unsigned)cell * (unsigned)NG;
  const int base = wdw * 10000;

  float m1 = -3e38f, m2 = -3e38f;
  int n1 = -1, n2 = -1;
  for (int c = t; c < 2500; c += 256) {
    const int n0 = base + c * 4;
    const float4 sv = *(const float4*)(sb + n0);     // coalesced 16B
    const unsigned bb0 = tfbits(ib + (unsigned)n0);
    const unsigned bb1 = tfbits(ib + (unsigned)(n0 + 1));
    const unsigned bb2 = tfbits(ib + (unsigned)(n0 + 2));
    const unsigned bb3 = tfbits(ib + (unsigned)(n0 + 3));
    const float s0 = sv.x + gumbel32(bb0);
    const float s1 = sv.y + gumbel32(bb1);
    const float s2 = sv.z + gumbel32(bb2);
    const float s3 = sv.w + gumbel32(bb3);
    if (s0 > m1) { m2 = m1; n2 = n1; m1 = s0; n1 = n0; }
    else if (s0 > m2) { m2 = s0; n2 = n0; }
    if (s1 > m1) { m2 = m1; n2 = n1; m1 = s1; n1 = n0 + 1; }
    else if (s1 > m2) { m2 = s1; n2 = n0 + 1; }
    if (s2 > m1) { m2 = m1; n2 = n1; m1 = s2; n1 = n0 + 2; }
    else if (s2 > m2) { m2 = s2; n2 = n0 + 2; }
    if (s3 > m1) { m2 = m1; n2 = n1; m1 = s3; n1 = n0 + 3; }
    else if (s3 > m2) { m2 = s3; n2 = n0 + 3; }
  }
  unsigned long long p1 = packscreen(m1, n1);
  unsigned long long p2 = packscreen(m2, n2);
  // wave top-2 butterfly: merge sorted pairs (p1>=p2), (q1>=q2)
  #pragma unroll
  for (int off = 32; off; off >>= 1) {
    unsigned long long q1 = __shfl_xor(p1, off, 64);
    unsigned long long q2 = __shfl_xor(p2, off, 64);
    if (q1 > p1) {
      unsigned long long t1 = p1;
      p1 = q1;
      p2 = (q2 > t1) ? q2 : t1;
    } else {
      p2 = (q1 > p2) ? q1 : p2;
    }
  }
  if (lane == 0) { R1s[wv] = p1; R2s[wv] = p2; }
  __syncthreads();
  if (t == 0) {
    unsigned long long P1 = R1s[0], P2 = R2s[0];
    #pragma unroll
    for (int w = 1; w < 4; ++w) {
      unsigned long long q1 = R1s[w], q2 = R2s[w];
      if (q1 > P1) {
        unsigned long long t1 = P1;
        P1 = q1;
        P2 = (q2 > t1) ? q2 : t1;
      } else {
        P2 = (q1 > P2) ? q1 : P2;
      }
    }
    const int w1 = (int)(P1 & 0xFFFFFFFFull);
    const int w2i = (int)(P2 & 0xFFFFFFFFull);
    const unsigned bb1 = tfbits(ib + (unsigned)w1);
    const float s1f = sb[w1];
    const float sc1 = s1f + gumbel32(bb1);
    unsigned long long pb = packcell((double)s1f + gumbel64(bb1), w1);
    if (w2i >= 0) {
      const unsigned bb2 = tfbits(ib + (unsigned)w2i);
      const float s2f = sb[w2i];
      const float sc2 = s2f + gumbel32(bb2);
      if ((sc1 - sc2) < 1e-4f) {
        const unsigned long long u2 =
            packcell((double)s2f + gumbel64(bb2), w2i);
        if (u2 > pb) pb = u2;
      }
    }
    atomicMax(&cells[cell], pb);
  }
}

// ---------- epilogue (fp32): 5 interleaved V-GEMVs per wave, softmax over K, context ----------
__global__ __launch_bounds__(256) void kfinal(
    const float* __restrict__ ge, const float* __restrict__ Wv,
    const float* __restrict__ bv, const float* __restrict__ Qm,
    const unsigned long long* __restrict__ cells, float* __restrict__ out) {
  const int b = blockIdx.x;
  const int t = threadIdx.x;
  const int wv = t >> 6;
  const int lane = t & 63;
  __shared__ float sc[20];
  __shared__ float ctxp[4][128];
  const float2 qv = ((const float2*)(Qm + b * 128))[lane];
  const float2 bvv = ((const float2*)bv)[lane];
  const float* gr[5];
  float2 V[5];
  #pragma unroll
  for (int j = 0; j < 5; ++j) {
    const unsigned long long cell = cells[b * 20 + wv * 5 + j];
    const int n = 32767 - (int)(cell & 0x7FFFull);
    gr[j] = ge + (size_t)n * 256;
    V[j] = bvv;
  }
  for (int f = 0; f < 256; f += 4) {
    const float2 w0 = ((const float2*)(Wv + (size_t)(f + 0) * 128))[lane];
    const float2 w1 = ((const float2*)(Wv + (size_t)(f + 1) * 128))[lane];
    const float2 w2_ = ((const float2*)(Wv + (size_t)(f + 2) * 128))[lane];
    const float2 w3 = ((const float2*)(Wv + (size_t)(f + 3) * 128))[lane];
    #pragma unroll
    for (int j = 0; j < 5; ++j) {
      const float4 gv = *(const float4*)(gr[j] + f);   // uniform -> s_load
      V[j].x = fmaf(gv.x, w0.x, V[j].x); V[j].y = fmaf(gv.x, w0.y, V[j].y);
      V[j].x = fmaf(gv.y, w1.x, V[j].x); V[j].y = fmaf(gv.y, w1.y, V[j].y);
      V[j].x = fmaf(gv.z, w2_.x, V[j].x); V[j].y = fmaf(gv.z, w2_.y, V[j].y);
      V[j].x = fmaf(gv.w, w3.x, V[j].x); V[j].y = fmaf(gv.w, w3.y, V[j].y);
    }
  }
  #pragma unroll
  for (int j = 0; j < 5; ++j) {
    float pr = qv.x * V[j].x + qv.y * V[j].y;
    #pragma unroll
    for (int off = 32; off; off >>= 1) pr += __shfl_xor(pr, off, 64);
    if (lane == 0) sc[wv * 5 + j] = pr * 0.08838834764831845f;  // 1/sqrt(128)
  }
  __syncthreads();
  float m = -3.0e38f;
  #pragma unroll
  for (int i = 0; i < 20; ++i) m = fmaxf(m, sc[i]);
  float s = 0.f;
  #pragma unroll
  for (int i = 0; i < 20; ++i) s += expf(sc[i] - m);
  const float inv = 1.0f / s;
  float c0 = 0.f, c1 = 0.f;
  #pragma unroll
  for (int j = 0; j < 5; ++j) {
    const float wk = expf(sc[wv * 5 + j] - m) * inv;
    c0 = fmaf(wk, V[j].x, c0);
    c1 = fmaf(wk, V[j].y, c1);
  }
  ctxp[wv][2 * lane] = c0;
  ctxp[wv][2 * lane + 1] = c1;
  __syncthreads();
  if (t < 128)
    out[b * 128 + t] = (ctxp[0][t] + ctxp[1][t]) + (ctxp[2][t] + ctxp[3][t]);
}

extern "C" void kernel_launch(void* const* d_in, const int* in_sizes, int n_in,
                              void* d_out, int out_size, void* d_ws, size_t ws_size,
                              hipStream_t stream) {
  (void)in_sizes; (void)n_in; (void)out_size; (void)ws_size;
  const float* pe = (const float*)d_in[0];
  const float* ge = (const float*)d_in[1];
  const float* Wq = (const float*)d_in[2];
  const float* bq = (const float*)d_in[3];
  const float* Wk = (const float*)d_in[4];
  const float* bk = (const float*)d_in[5];
  const float* Wv = (const float*)d_in[6];
  const float* bvp = (const float*)d_in[7];
  const float* W1 = (const float*)d_in[8];
  const float* b1 = (const float*)d_in[9];
  const float* w2 = (const float*)d_in[10];
  // d_in[11] = b2: uniform over n -> cancels in argmax; absent from output path.

  char* w = (char*)d_ws;
  float* Wf32 = (float*)w;                               // 131072 B
  double* qbT = (double*)(w + 131072);                   // 65536 B
  float* Qm = (float*)(w + 196608);                      // 32768 B
  unsigned long long* cells =
      (unsigned long long*)(w + 229376);                 // 10240 B
  double2* c12 = (double2*)(w + 239616);                 // 2048 B
  float* simg = (float*)(w + 262144);                    // 5,120,000 B (~5.4 MB total)
  float* out = (float*)d_out;

  kprep<<<dim3(321), dim3(128), 0, stream>>>(pe, Wq, bq, Wk, bk, W1, b1, w2,
                                             Wf32, qbT, Qm, cells, c12);
  ksim<<<dim3(1250), dim3(256), 0, stream>>>(ge, Wf32, qbT, c12, simg);
  kargmax<<<dim3(2560), dim3(256), 0, stream>>>(simg, cells);
  kfinal<<<dim3(64), dim3(256), 0, stream>>>(ge, Wv, bvp, Qm, cells, out);
}